// Round 1
// 482.147 us; speedup vs baseline: 1.0366x; 1.0366x over previous
//
#include <hip/hip_runtime.h>

typedef unsigned int u32;

#define BB 4
#define HH 180
#define WWD 320
#define HW_ 57600            // H*W
#define TENSOR_ 14745600     // B*C*H*W
#define XM 84                // xi row stride per k-pair (floats): [32][40][2]+pad
#define QS 68                // qf row stride (Q u-major [40][68])

// ---- module-scope scratch ----
__device__ __align__(16) float g_gap[512];      // [side][b][c]
__device__ __align__(16) float g_bagg[512];     // [side][b][o]
__device__ __align__(16) float g_swn[128];      // [side][o]
__device__ __align__(16) float g_sb[128];       // [side][o]
__device__ __align__(16) float g_waggT[32768];  // [side][b][i][o]  (transposed)
__device__ __align__(16) float g_w1fT[8192];    // [side][k][o] LN-folded p1 (transposed)
__device__ __align__(16) float g_p2T[8192];     // [side][k][o] p2 (transposed)

// ---------------- kernel 1: global average pool -> g_gap
__global__ __launch_bounds__(256) void gap_kernel(const float* __restrict__ xl,
                                                  const float* __restrict__ xr) {
    int job = blockIdx.x;                 // side*256 + b*64 + c
    int side = job >> 8;
    int bc = job & 255;
    const float4* p = (const float4*)((side ? xr : xl) + (size_t)bc * HW_);
    float s = 0.f;
    for (int i = threadIdx.x; i < 14400; i += 256) {
        float4 v = p[i];
        s += v.x + v.y + v.z + v.w;
    }
    #pragma unroll
    for (int off = 32; off > 0; off >>= 1) s += __shfl_down(s, off, 64);
    __shared__ float red[4];
    int lane = threadIdx.x & 63, wv = threadIdx.x >> 6;
    if (lane == 0) red[wv] = s;
    __syncthreads();
    if (threadIdx.x == 0)
        g_gap[job] = (red[0] + red[1] + red[2] + red[3]) * (1.f / 57600.f);
}

// ---------------- kernel 2: expert mixture + transposed weights + waggT + bagg
__global__ __launch_bounds__(256) void prep_kernel(
    const float* __restrict__ nlw, const float* __restrict__ nlb,
    const float* __restrict__ nrw, const float* __restrict__ nrb,
    const float* __restrict__ lp1w, const float* __restrict__ rp1w,
    const float* __restrict__ lp2w, const float* __restrict__ rp2w,
    const float* __restrict__ lf1w, const float* __restrict__ lf1b,
    const float* __restrict__ lf2w, const float* __restrict__ lf2b,
    const float* __restrict__ lfbias,
    const float* __restrict__ rf1w, const float* __restrict__ rf1b,
    const float* __restrict__ rf2w, const float* __restrict__ rf2b,
    const float* __restrict__ rfbias,
    const float* __restrict__ lfW, const float* __restrict__ rfW)
{
    __shared__ float att[2][4][3];
    int t = threadIdx.x;
    if (t < 8) {
        int side = t >> 2, b = t & 3;
        const float* f1w = side ? rf1w : lf1w;
        const float* f1b = side ? rf1b : lf1b;
        const float* f2w = side ? rf2w : lf2w;
        const float* f2bv = side ? rf2b : lf2b;
        const float* g = g_gap + side*256 + b*64;
        float a1[3];
        #pragma unroll
        for (int k = 0; k < 3; k++) {
            float s = f1b[k];
            for (int c = 0; c < 64; c++) s += g[c] * f1w[k*64 + c];
            a1[k] = fmaxf(s, 0.f);
        }
        float a2[3];
        #pragma unroll
        for (int j = 0; j < 3; j++) {
            float s = f2bv[j];
            #pragma unroll
            for (int k = 0; k < 3; k++) s += a1[k] * f2w[j*3 + k];
            a2[j] = s;
        }
        float m = fmaxf(fmaxf(a2[0], a2[1]), a2[2]);
        float e0 = __expf(a2[0]-m), e1 = __expf(a2[1]-m), e2 = __expf(a2[2]-m);
        float inv = 1.f / (e0 + e1 + e2);
        att[side][b][0] = e0*inv; att[side][b][1] = e1*inv; att[side][b][2] = e2*inv;
    }
    __syncthreads();

    if (blockIdx.x < 16) {
        int flat = blockIdx.x * 2048 + t * 8;
        int side = flat >> 14, bb = (flat >> 12) & 3, i = (flat >> 6) & 63, o0 = flat & 63;
        const float* Wp = side ? rfW : lfW;
        float a0 = att[side][bb][0], a1 = att[side][bb][1], a2 = att[side][bb][2];
        #pragma unroll
        for (int q = 0; q < 8; q++) {
            int o = o0 + q;
            g_waggT[flat+q] = a0*Wp[o*64+i] + a1*Wp[4096+o*64+i] + a2*Wp[8192+o*64+i];
        }
    } else {
        if (t < 128) {
            int side = t >> 6, o = t & 63;
            const float* w1 = side ? rp1w : lp1w;
            const float* w2 = side ? rp2w : lp2w;
            const float* nw = side ? nrw : nlw;
            const float* nb = side ? nrb : nlb;
            float s_wn = 0.f, s_b = 0.f;
            for (int i = 0; i < 64; i++) {
                float wf = w1[o*64 + i];
                float wp = wf * nw[i];
                g_w1fT[side*4096 + i*64 + o] = wp;
                g_p2T [side*4096 + i*64 + o] = w2[o*64 + i];
                s_wn += wp;
                s_b  += wf * nb[i];
            }
            g_swn[side*64 + o] = s_wn;
            g_sb[side*64 + o]  = s_b;
        }
        for (int idx = t; idx < 512; idx += 256) {
            int side = idx >> 8, r = idx & 255, b = r >> 6, o = r & 63;
            const float* bp = side ? rfbias : lfbias;
            g_bagg[idx] = att[side][b][0]*bp[o]
                        + att[side][b][1]*bp[64+o]
                        + att[side][b][2]*bp[128+o];
        }
    }
}

// ---------------- kernel 3: fused LN->proj->cross-attn->dynamic conv->residual
// block = one (b,h) row x 4 width-chunks (40 px); 4 waves.
// xi: x in k-pair-interleaved layout [m=k/2][px][k&1], stride XM=84. Lives whole kernel.
// qf: Q u-major [u][QS=68] for attention, then reused as F k-pair layout [m][px][par].
__global__ __launch_bounds__(256, 3) void main_kernel(
    const float* __restrict__ xl_g, const float* __restrict__ xr_g,
    const float* __restrict__ lp1b, const float* __restrict__ rp1b,
    const float* __restrict__ lp2b, const float* __restrict__ rp2b,
    const float* __restrict__ beta, const float* __restrict__ gamma,
    float* __restrict__ out)
{
    __shared__ __align__(16) float xi0[2688];
    __shared__ __align__(16) float xi1[2688];
    __shared__ __align__(16) float qf0[2720];
    __shared__ __align__(16) float qf1[2720];
    __shared__ float attn[4][10][10];
    __shared__ float Ar[4][10][10];   // softmax over v
    __shared__ float Al[4][10][10];   // softmax over u
    __shared__ float muA[40], rsA[40], muB[40], rsB[40];

    int t = threadIdx.x;
    int wv = t >> 6, lane = t & 63;
    int bid = blockIdx.x;
    int b  = bid / (HH*8);
    int r0 = bid % (HH*8);
    int h  = r0 / 8;
    int g  = r0 % 8;
    int w0 = g * 40;

    // ---- P0: stage x into k-pair-interleaved LDS ----
    // job = (tensor, m, seg): load both channels of k-pair m, write 2x ds_write_b128
    for (int idx = t; idx < 640; idx += 256) {
        int tensor = idx / 320;
        int r2 = idx - tensor*320;
        int m = r2 / 10, seg = r2 - m*10;          // seg: 10 float4 per 40-px row
        const float* src = (tensor ? xr_g : xl_g)
                         + (((size_t)(b*64 + 2*m)*HH + h)*WWD + w0 + seg*4);
        float4 a = *(const float4*)(src);
        float4 c = *(const float4*)(src + HW_);    // channel 2m+1, same pixels
        float* dst = (tensor ? xi1 : xi0) + m*XM + seg*8;
        *(float4*)(dst)     = make_float4(a.x, c.x, a.y, c.y);
        *(float4*)(dst + 4) = make_float4(a.z, c.z, a.w, c.w);
    }
    __syncthreads();

    // ---- P1: LN stats, 20 lanes x 4 waves cover 2 sides x 40 px ----
    if (lane < 20) {
        int side = wv >> 1;
        int u = (wv & 1)*20 + lane;
        const float* xx = side ? xi1 : xi0;
        float s = 0.f, s2 = 0.f;
        for (int m = 0; m < 32; m++) {
            float v0 = xx[m*XM + u*2];
            float v1 = xx[m*XM + u*2 + 1];
            s += v0 + v1; s2 += v0*v0 + v1*v1;
        }
        float mu = s * (1.f/64.f);
        float var = fmaxf(s2 * (1.f/64.f) - mu*mu, 0.f);
        float rs = rsqrtf(var + 1e-6f);
        if (side) { muB[u] = mu; rsB[u] = rs; } else { muA[u] = mu; rsA[u] = rs; }
    }
    __syncthreads();

    // ---- P2: 4 GEMMs (Ql,Qr,Vl,Vr), o-tile 8 x u-tile 5, k-paired ----
    int og = lane & 7, ug = lane >> 3;
    int ob = og * 8, ub = ug * 5;

    float acc[8][5];
    #pragma unroll
    for (int r = 0; r < 8; r++)
        #pragma unroll
        for (int j = 0; j < 5; j++) acc[r][j] = 0.f;

    {
        const float* wT; const float* xs;
        switch (wv) {
            case 0:  wT = g_w1fT;        xs = xi0; break;
            case 1:  wT = g_w1fT + 4096; xs = xi1; break;
            case 2:  wT = g_p2T;         xs = xi0; break;
            default: wT = g_p2T + 4096;  xs = xi1; break;
        }
        __builtin_amdgcn_s_setprio(1);
        for (int m = 0; m < 32; m++) {
            const float* wp = wT + m*128;
            float4 wa0 = *(const float4*)(wp + ob);
            float4 wa1 = *(const float4*)(wp + ob + 4);
            float4 wb0 = *(const float4*)(wp + 64 + ob);
            float4 wb1 = *(const float4*)(wp + 64 + ob + 4);
            float2 xv[5];
            const float* xrow = xs + m*XM + ub*2;
            #pragma unroll
            for (int j = 0; j < 5; j++) xv[j] = *(const float2*)(xrow + j*2);
            float wa[8] = {wa0.x,wa0.y,wa0.z,wa0.w, wa1.x,wa1.y,wa1.z,wa1.w};
            float wb[8] = {wb0.x,wb0.y,wb0.z,wb0.w, wb1.x,wb1.y,wb1.z,wb1.w};
            #pragma unroll
            for (int r = 0; r < 8; r++)
                #pragma unroll
                for (int j = 0; j < 5; j++) {
                    acc[r][j] = fmaf(wa[r], xv[j].x, acc[r][j]);
                    acc[r][j] = fmaf(wb[r], xv[j].y, acc[r][j]);
                }
        }
        __builtin_amdgcn_s_setprio(0);
    }

    if (wv < 2) {   // Q epilogue (LN fold) -> qf u-major
        const float* mu  = wv ? muB : muA;
        const float* rs  = wv ? rsB : rsA;
        const float* p1b = wv ? rp1b : lp1b;
        float* qdst = wv ? qf1 : qf0;
        float swl[8], sbl[8];
        #pragma unroll
        for (int r = 0; r < 8; r++) {
            swl[r] = g_swn[wv*64 + ob + r];
            sbl[r] = g_sb[wv*64 + ob + r] + p1b[ob + r];
        }
        #pragma unroll
        for (int j = 0; j < 5; j++) {
            int u = ub + j;
            float rsv = rs[u], muv = mu[u];
            float e[8];
            #pragma unroll
            for (int r = 0; r < 8; r++)
                e[r] = rsv*(acc[r][j] - muv*swl[r]) + sbl[r];
            *(float4*)(qdst + u*QS + ob)     = make_float4(e[0],e[1],e[2],e[3]);
            *(float4*)(qdst + u*QS + ob + 4) = make_float4(e[4],e[5],e[6],e[7]);
        }
    } else {        // V: add bias, stay in registers
        const float* p2b = (wv == 2) ? lp2b : rp2b;
        #pragma unroll
        for (int r = 0; r < 8; r++) {
            float bv = p2b[ob + r];
            #pragma unroll
            for (int j = 0; j < 5; j++) acc[r][j] += bv;
        }
    }
    __syncthreads();

    // ---- P3: block-diag attention scores; wave = chunk ----
    for (int p = lane; p < 100; p += 64) {
        int uu = p / 10, vv = p - (p/10)*10;
        const float4* ra = (const float4*)(qf0 + (wv*10 + uu)*QS);
        const float4* rb = (const float4*)(qf1 + (wv*10 + vv)*QS);
        float s = 0.f;
        #pragma unroll
        for (int cc = 0; cc < 16; cc++) {
            float4 a = ra[cc], q = rb[cc];
            s += a.x*q.x + a.y*q.y + a.z*q.z + a.w*q.w;
        }
        attn[wv][uu][vv] = s * 0.125f;
    }
    __syncthreads();

    if (t < 40) {                      // softmax over v -> Ar
        int k = t / 10, uu = t - (t/10)*10;
        float m = attn[k][uu][0];
        #pragma unroll
        for (int v2 = 1; v2 < 10; v2++) m = fmaxf(m, attn[k][uu][v2]);
        float e[10]; float ssum = 0.f;
        #pragma unroll
        for (int v2 = 0; v2 < 10; v2++) { e[v2] = __expf(attn[k][uu][v2] - m); ssum += e[v2]; }
        float inv = 1.f / ssum;
        #pragma unroll
        for (int v2 = 0; v2 < 10; v2++) Ar[k][uu][v2] = e[v2]*inv;
    } else if (t >= 64 && t < 104) {   // softmax over u -> Al
        int t2 = t - 64;
        int k = t2 / 10, vv = t2 - (t2/10)*10;
        float m = attn[k][0][vv];
        #pragma unroll
        for (int u2 = 1; u2 < 10; u2++) m = fmaxf(m, attn[k][u2][vv]);
        float e[10]; float ssum = 0.f;
        #pragma unroll
        for (int u2 = 0; u2 < 10; u2++) { e[u2] = __expf(attn[k][u2][vv] - m); ssum += e[u2]; }
        float inv = 1.f / ssum;
        #pragma unroll
        for (int u2 = 0; u2 < 10; u2++) Al[k][u2][vv] = e[u2]*inv;
    }
    __syncthreads();

    // ---- P4: F from register V, half-exchange via shfl; write k-paired into qf ----
    if (wv == 3) {          // Vr -> F_r2l*beta -> qf0 (for side-0 output)
        int k = ug >> 1, half = ug & 1, vb = half*5;
        float sc[8];
        #pragma unroll
        for (int r = 0; r < 8; r++) sc[r] = beta[ob + r];
        #pragma unroll
        for (int j2 = 0; j2 < 5; j2++) {
            int u1 = vb + j2;          // my output slice
            int u2 = 5 - vb + j2;      // partner's output slice
            float a1[5], a2[5];
            #pragma unroll
            for (int j = 0; j < 5; j++) { a1[j] = Ar[k][u1][vb+j]; a2[j] = Ar[k][u2][vb+j]; }
            #pragma unroll
            for (int r = 0; r < 8; r++) {
                float sA = 0.f, sB = 0.f;
                #pragma unroll
                for (int j = 0; j < 5; j++) {
                    sA = fmaf(a1[j], acc[r][j], sA);
                    sB = fmaf(a2[j], acc[r][j], sB);
                }
                float recv = __shfl_xor(sB, 8, 64);
                int o = ob + r;
                qf0[(o>>1)*XM + (k*10 + u1)*2 + (o&1)] = (sA + recv) * sc[r];
            }
        }
    } else if (wv == 2) {   // Vl -> F_l2r*gamma -> qf1 (for side-1 output)
        int k = ug >> 1, half = ug & 1, vb = half*5;
        float sc[8];
        #pragma unroll
        for (int r = 0; r < 8; r++) sc[r] = gamma[ob + r];
        #pragma unroll
        for (int j2 = 0; j2 < 5; j2++) {
            int u1 = vb + j2;
            int u2 = 5 - vb + j2;
            float a1[5], a2[5];
            #pragma unroll
            for (int j = 0; j < 5; j++) { a1[j] = Al[k][vb+j][u1]; a2[j] = Al[k][vb+j][u2]; }
            #pragma unroll
            for (int r = 0; r < 8; r++) {
                float sA = 0.f, sB = 0.f;
                #pragma unroll
                for (int j = 0; j < 5; j++) {
                    sA = fmaf(a1[j], acc[r][j], sA);
                    sB = fmaf(a2[j], acc[r][j], sB);
                }
                float recv = __shfl_xor(sB, 8, 64);
                int o = ob + r;
                qf1[(o>>1)*XM + (k*10 + u1)*2 + (o&1)] = (sA + recv) * sc[r];
            }
        }
    }
    __syncthreads();

    // ---- P5: dynamic conv + residual(LDS) + store; ALL 4 waves ----
    // wave = (side, o-half): waves 0,1 -> side 0 (o 0..31 / 32..63); 2,3 -> side 1
    {
        int side = wv >> 1;
        int oh   = wv & 1;
        int ob4  = oh*32 + og*4;
        const float* Fb   = side ? qf1 : qf0;
        const float* xres = side ? xi1 : xi0;
        const float* wrow = g_waggT + (size_t)(side*4 + b)*4096;
        float acc5[4][5];
        #pragma unroll
        for (int r = 0; r < 4; r++)
            #pragma unroll
            for (int j = 0; j < 5; j++) acc5[r][j] = 0.f;
        __builtin_amdgcn_s_setprio(1);
        for (int m = 0; m < 32; m++) {
            const float* wp = wrow + m*128;
            float4 wa4 = *(const float4*)(wp + ob4);
            float4 wb4 = *(const float4*)(wp + 64 + ob4);
            float2 xv[5];
            const float* frow = Fb + m*XM + ub*2;
            #pragma unroll
            for (int j = 0; j < 5; j++) xv[j] = *(const float2*)(frow + j*2);
            float wa[4] = {wa4.x,wa4.y,wa4.z,wa4.w};
            float wb[4] = {wb4.x,wb4.y,wb4.z,wb4.w};
            #pragma unroll
            for (int r = 0; r < 4; r++)
                #pragma unroll
                for (int j = 0; j < 5; j++) {
                    acc5[r][j] = fmaf(wa[r], xv[j].x, acc5[r][j]);
                    acc5[r][j] = fmaf(wb[r], xv[j].y, acc5[r][j]);
                }
        }
        __builtin_amdgcn_s_setprio(0);
        #pragma unroll
        for (int r = 0; r < 4; r++) {
            int o = ob4 + r;
            float bg = g_bagg[side*256 + b*64 + o];
            float* op = out + (size_t)side*TENSOR_ + (((size_t)(b*64+o)*HH + h)*WWD + w0 + ub);
            #pragma unroll
            for (int j = 0; j < 5; j++)
                op[j] = acc5[r][j] + bg + xres[(o>>1)*XM + (ub+j)*2 + (o&1)];
        }
    }
}

extern "C" void kernel_launch(void* const* d_in, const int* in_sizes, int n_in,
                              void* d_out, int out_size, void* d_ws, size_t ws_size,
                              hipStream_t stream) {
    (void)in_sizes; (void)n_in; (void)out_size; (void)d_ws; (void)ws_size;
    const float* x_l = (const float*)d_in[0];
    const float* x_r = (const float*)d_in[1];

    gap_kernel<<<512, 256, 0, stream>>>(x_l, x_r);
    prep_kernel<<<17, 256, 0, stream>>>(
        (const float*)d_in[2],  (const float*)d_in[3],
        (const float*)d_in[4],  (const float*)d_in[5],
        (const float*)d_in[6],  (const float*)d_in[8],
        (const float*)d_in[10], (const float*)d_in[12],
        (const float*)d_in[16], (const float*)d_in[17],
        (const float*)d_in[18], (const float*)d_in[19], (const float*)d_in[21],
        (const float*)d_in[22], (const float*)d_in[23],
        (const float*)d_in[24], (const float*)d_in[25], (const float*)d_in[27],
        (const float*)d_in[20], (const float*)d_in[26]);
    main_kernel<<<BB*HH*8, 256, 0, stream>>>(x_l, x_r,
        (const float*)d_in[7],  (const float*)d_in[9],
        (const float*)d_in[11], (const float*)d_in[13],
        (const float*)d_in[14], (const float*)d_in[15],
        (float*)d_out);
}

// Round 3
// 436.520 us; speedup vs baseline: 1.1450x; 1.1045x over previous
//
#include <hip/hip_runtime.h>

typedef unsigned int u32;
typedef __fp16 h2 __attribute__((ext_vector_type(2)));

#define BB 4
#define HH 180
#define WWD 320
#define HW_ 57600            // H*W
#define TENSOR_ 14745600     // B*C*H*W
#define XST 44               // xi row stride per k-pair (h2 units): [32][40]+4 pad
#define QST 36               // qf row stride for Q (h2 units): [40][32]+4 pad

union U4 { float4 f; h2 h[4]; };

// ---- module-scope scratch ----
__device__ __align__(16) float g_gap[512];      // [side][b][c]
__device__ __align__(16) float g_bagg[512];     // [side][b][o]
__device__ __align__(16) float g_swn[128];      // [side][o] sum of rounded folded w1
__device__ __align__(16) float g_sb[128];       // [side][o]
__device__ __align__(16) h2 g_w1fTh[4096];      // [side][m][o] LN-folded p1, fp16 k-pairs
__device__ __align__(16) h2 g_p2Th[4096];       // [side][m][o] p2, fp16 k-pairs
__device__ __align__(16) h2 g_waggTh[16384];    // [side][b][m][o] dyn conv W, fp16 k-pairs

// ---------------- kernel 1: global average pool -> g_gap
__global__ __launch_bounds__(256) void gap_kernel(const float* __restrict__ xl,
                                                  const float* __restrict__ xr) {
    int job = blockIdx.x;                 // side*256 + b*64 + c
    int side = job >> 8;
    int bc = job & 255;
    const float4* p = (const float4*)((side ? xr : xl) + (size_t)bc * HW_);
    float s = 0.f;
    for (int i = threadIdx.x; i < 14400; i += 256) {
        float4 v = p[i];
        s += v.x + v.y + v.z + v.w;
    }
    #pragma unroll
    for (int off = 32; off > 0; off >>= 1) s += __shfl_down(s, off, 64);
    __shared__ float red[4];
    int lane = threadIdx.x & 63, wv = threadIdx.x >> 6;
    if (lane == 0) red[wv] = s;
    __syncthreads();
    if (threadIdx.x == 0)
        g_gap[job] = (red[0] + red[1] + red[2] + red[3]) * (1.f / 57600.f);
}

// ---------------- kernel 2: expert mixture + fp16 transposed weight tables + bagg
__global__ __launch_bounds__(256) void prep_kernel(
    const float* __restrict__ nlw, const float* __restrict__ nlb,
    const float* __restrict__ nrw, const float* __restrict__ nrb,
    const float* __restrict__ lp1w, const float* __restrict__ rp1w,
    const float* __restrict__ lp2w, const float* __restrict__ rp2w,
    const float* __restrict__ lf1w, const float* __restrict__ lf1b,
    const float* __restrict__ lf2w, const float* __restrict__ lf2b,
    const float* __restrict__ lfbias,
    const float* __restrict__ rf1w, const float* __restrict__ rf1b,
    const float* __restrict__ rf2w, const float* __restrict__ rf2b,
    const float* __restrict__ rfbias,
    const float* __restrict__ lfW, const float* __restrict__ rfW)
{
    __shared__ float att[2][4][3];
    int t = threadIdx.x;
    if (t < 8) {
        int side = t >> 2, b = t & 3;
        const float* f1w = side ? rf1w : lf1w;
        const float* f1b = side ? rf1b : lf1b;
        const float* f2w = side ? rf2w : lf2w;
        const float* f2bv = side ? rf2b : lf2b;
        const float* g = g_gap + side*256 + b*64;
        float a1[3];
        #pragma unroll
        for (int k = 0; k < 3; k++) {
            float s = f1b[k];
            for (int c = 0; c < 64; c++) s += g[c] * f1w[k*64 + c];
            a1[k] = fmaxf(s, 0.f);
        }
        float a2[3];
        #pragma unroll
        for (int j = 0; j < 3; j++) {
            float s = f2bv[j];
            #pragma unroll
            for (int k = 0; k < 3; k++) s += a1[k] * f2w[j*3 + k];
            a2[j] = s;
        }
        float m = fmaxf(fmaxf(a2[0], a2[1]), a2[2]);
        float e0 = __expf(a2[0]-m), e1 = __expf(a2[1]-m), e2 = __expf(a2[2]-m);
        float inv = 1.f / (e0 + e1 + e2);
        att[side][b][0] = e0*inv; att[side][b][1] = e1*inv; att[side][b][2] = e2*inv;
    }
    __syncthreads();

    if (blockIdx.x < 16) {
        // Wagg fp16 k-pair table: [side][b][m][o], 4 h2 per thread
        int flat2 = blockIdx.x * 1024 + t * 4;
        int side = flat2 >> 13, bb = (flat2 >> 11) & 3, m = (flat2 >> 6) & 31, o0 = flat2 & 63;
        const float* Wp = side ? rfW : lfW;
        float a0 = att[side][bb][0], a1 = att[side][bb][1], a2 = att[side][bb][2];
        #pragma unroll
        for (int q = 0; q < 4; q++) {
            int o = o0 + q;
            float wi0 = a0*Wp[o*64+2*m]   + a1*Wp[4096+o*64+2*m]   + a2*Wp[8192+o*64+2*m];
            float wi1 = a0*Wp[o*64+2*m+1] + a1*Wp[4096+o*64+2*m+1] + a2*Wp[8192+o*64+2*m+1];
            g_waggTh[((side*4+bb)*32 + m)*64 + o] = __builtin_amdgcn_cvt_pkrtz(wi0, wi1);
        }
    } else {
        if (t < 128) {
            int side = t >> 6, o = t & 63;
            const float* w1 = side ? rp1w : lp1w;
            const float* w2 = side ? rp2w : lp2w;
            const float* nw = side ? nrw : nlw;
            const float* nb = side ? nrb : nlb;
            float s_wn = 0.f, s_b = 0.f;
            for (int m = 0; m < 32; m++) {
                float wf0 = w1[o*64 + 2*m],   wf1 = w1[o*64 + 2*m+1];
                float wp0 = wf0 * nw[2*m],    wp1 = wf1 * nw[2*m+1];
                h2 hw = __builtin_amdgcn_cvt_pkrtz(wp0, wp1);
                g_w1fTh[side*2048 + m*64 + o] = hw;
                g_p2Th [side*2048 + m*64 + o] =
                    __builtin_amdgcn_cvt_pkrtz(w2[o*64+2*m], w2[o*64+2*m+1]);
                s_wn += (float)hw.x + (float)hw.y;   // consistent with rounded weights
                s_b  += wf0*nb[2*m] + wf1*nb[2*m+1];
            }
            g_swn[side*64 + o] = s_wn;
            g_sb[side*64 + o]  = s_b;
        }
        for (int idx = t; idx < 512; idx += 256) {
            int side = idx >> 8, r = idx & 255, b = r >> 6, o = r & 63;
            const float* bp = side ? rfbias : lfbias;
            g_bagg[idx] = att[side][b][0]*bp[o]
                        + att[side][b][1]*bp[64+o]
                        + att[side][b][2]*bp[128+o];
        }
    }
}

// ---------------- kernel 3: fused LN->proj->cross-attn->dynamic conv->residual
// block = one (b,h) row x 4 width-chunks (40 px); 4 waves.
// xi: x as fp16 k-pairs [m=i/2][px] (h2 = (ch even, ch odd)), stride XST. Dead after P2.
// qf: Q as fp16 channel-pairs [u][c2], stride QST; reused as F in xi-style layout for P5.
__global__ __launch_bounds__(256, 5) void main_kernel(
    const float* __restrict__ xl_g, const float* __restrict__ xr_g,
    const float* __restrict__ lp1b, const float* __restrict__ rp1b,
    const float* __restrict__ lp2b, const float* __restrict__ rp2b,
    const float* __restrict__ beta, const float* __restrict__ gamma,
    float* __restrict__ out)
{
    __shared__ __align__(16) h2 xi0[1408];   // 32*XST
    __shared__ __align__(16) h2 xi1[1408];
    __shared__ __align__(16) h2 qf0[1440];   // max(40*QST, 32*XST)
    __shared__ __align__(16) h2 qf1[1440];
    __shared__ float attn[4][10][10];
    __shared__ float Ar[4][10][10];   // softmax over v
    __shared__ float Al[4][10][10];   // softmax over u
    __shared__ float muA[40], rsA[40], muB[40], rsB[40];

    int t = threadIdx.x;
    int wv = t >> 6, lane = t & 63;
    int bid = blockIdx.x;
    int b  = bid / (HH*8);
    int r0 = bid % (HH*8);
    int h  = r0 / 8;
    int g  = r0 % 8;
    int w0 = g * 40;

    // ---- P0: stage x -> fp16 k-pair LDS (cvt_pkrtz, one b128 write per job) ----
    for (int idx = t; idx < 640; idx += 256) {
        int tensor = idx / 320;
        int r2 = idx - tensor*320;
        int m = r2 / 10, seg = r2 - m*10;
        const float* src = (tensor ? xr_g : xl_g)
                         + (((size_t)(b*64 + 2*m)*HH + h)*WWD + w0 + seg*4);
        float4 a = *(const float4*)(src);
        float4 c = *(const float4*)(src + HW_);    // odd channel, same pixels
        U4 u;
        u.h[0] = __builtin_amdgcn_cvt_pkrtz(a.x, c.x);
        u.h[1] = __builtin_amdgcn_cvt_pkrtz(a.y, c.y);
        u.h[2] = __builtin_amdgcn_cvt_pkrtz(a.z, c.z);
        u.h[3] = __builtin_amdgcn_cvt_pkrtz(a.w, c.w);
        h2* dst = (tensor ? xi1 : xi0) + m*XST + seg*4;
        *(float4*)dst = u.f;
    }
    __syncthreads();

    // ---- P1: LN stats via dot2; 20 lanes x 4 waves cover 2 sides x 40 px ----
    if (lane < 20) {
        int side = wv >> 1;
        int u = (wv & 1)*20 + lane;
        const h2* xx = side ? xi1 : xi0;
        h2 one2; one2.x = (__fp16)1.f; one2.y = (__fp16)1.f;
        float s_0 = 0.f, s_1 = 0.f, q_0 = 0.f, q_1 = 0.f;
        for (int m = 0; m < 32; m += 2) {
            h2 v0 = xx[m*XST + u];
            h2 v1 = xx[(m+1)*XST + u];
            s_0 = __builtin_amdgcn_fdot2(v0, one2, s_0, false);
            q_0 = __builtin_amdgcn_fdot2(v0, v0,   q_0, false);
            s_1 = __builtin_amdgcn_fdot2(v1, one2, s_1, false);
            q_1 = __builtin_amdgcn_fdot2(v1, v1,   q_1, false);
        }
        float s = s_0 + s_1, s2 = q_0 + q_1;
        float mu = s * (1.f/64.f);
        float var = fmaxf(s2 * (1.f/64.f) - mu*mu, 0.f);
        float rs = rsqrtf(var + 1e-6f);
        if (side) { muB[u] = mu; rsB[u] = rs; } else { muA[u] = mu; rsA[u] = rs; }
    }
    __syncthreads();

    // ---- P2: 4 GEMMs (Ql,Qr,Vl,Vr) via dot2; o-tile 8 x u-tile 5 ----
    int og = lane & 7, ug = lane >> 3;
    int ob = og * 8, ub = ug * 5;

    float acc[8][5];
    #pragma unroll
    for (int r = 0; r < 8; r++)
        #pragma unroll
        for (int j = 0; j < 5; j++) acc[r][j] = 0.f;

    {
        const h2* wT; const h2* xs;
        switch (wv) {
            case 0:  wT = g_w1fTh;        xs = xi0; break;
            case 1:  wT = g_w1fTh + 2048; xs = xi1; break;
            case 2:  wT = g_p2Th;         xs = xi0; break;
            default: wT = g_p2Th + 2048;  xs = xi1; break;
        }
        __builtin_amdgcn_s_setprio(1);
        for (int m = 0; m < 32; m++) {
            const h2* wp = wT + m*64 + ob;
            U4 w0u, w1u;
            w0u.f = *(const float4*)(wp);
            w1u.f = *(const float4*)(wp + 4);
            h2 xv[5];
            const h2* xrow = xs + m*XST + ub;
            #pragma unroll
            for (int j = 0; j < 5; j++) xv[j] = xrow[j];
            h2 wa[8] = {w0u.h[0],w0u.h[1],w0u.h[2],w0u.h[3],
                        w1u.h[0],w1u.h[1],w1u.h[2],w1u.h[3]};
            #pragma unroll
            for (int r = 0; r < 8; r++)
                #pragma unroll
                for (int j = 0; j < 5; j++)
                    acc[r][j] = __builtin_amdgcn_fdot2(wa[r], xv[j], acc[r][j], false);
        }
        __builtin_amdgcn_s_setprio(0);
    }

    if (wv < 2) {   // Q epilogue (LN fold, f32) -> pack fp16 channel-pairs
        const float* mu  = wv ? muB : muA;
        const float* rs  = wv ? rsB : rsA;
        const float* p1b = wv ? rp1b : lp1b;
        h2* qdst = wv ? qf1 : qf0;
        float swl[8], sbl[8];
        #pragma unroll
        for (int r = 0; r < 8; r++) {
            swl[r] = g_swn[wv*64 + ob + r];
            sbl[r] = g_sb[wv*64 + ob + r] + p1b[ob + r];
        }
        #pragma unroll
        for (int j = 0; j < 5; j++) {
            int u = ub + j;
            float rsv = rs[u], muv = mu[u];
            float e[8];
            #pragma unroll
            for (int r = 0; r < 8; r++)
                e[r] = rsv*(acc[r][j] - muv*swl[r]) + sbl[r];
            U4 q;
            q.h[0] = __builtin_amdgcn_cvt_pkrtz(e[0], e[1]);
            q.h[1] = __builtin_amdgcn_cvt_pkrtz(e[2], e[3]);
            q.h[2] = __builtin_amdgcn_cvt_pkrtz(e[4], e[5]);
            q.h[3] = __builtin_amdgcn_cvt_pkrtz(e[6], e[7]);
            *(float4*)(qdst + u*QST + og*4) = q.f;
        }
    } else {        // V: add bias, stay in f32 registers
        const float* p2b = (wv == 2) ? lp2b : rp2b;
        #pragma unroll
        for (int r = 0; r < 8; r++) {
            float bv = p2b[ob + r];
            #pragma unroll
            for (int j = 0; j < 5; j++) acc[r][j] += bv;
        }
    }
    __syncthreads();

    // ---- P3: block-diag attention scores via dot2; wave = chunk ----
    for (int p = lane; p < 100; p += 64) {
        int uu = p / 10, vv = p - (p/10)*10;
        const h2* ra = qf0 + (wv*10 + uu)*QST;
        const h2* rb = qf1 + (wv*10 + vv)*QST;
        float sa = 0.f, sb = 0.f, sc = 0.f, sd = 0.f;
        #pragma unroll
        for (int c2 = 0; c2 < 32; c2 += 4) {
            sa = __builtin_amdgcn_fdot2(ra[c2],   rb[c2],   sa, false);
            sb = __builtin_amdgcn_fdot2(ra[c2+1], rb[c2+1], sb, false);
            sc = __builtin_amdgcn_fdot2(ra[c2+2], rb[c2+2], sc, false);
            sd = __builtin_amdgcn_fdot2(ra[c2+3], rb[c2+3], sd, false);
        }
        attn[wv][uu][vv] = ((sa+sb)+(sc+sd)) * 0.125f;
    }
    __syncthreads();

    if (t < 40) {                      // softmax over v -> Ar
        int k = t / 10, uu = t - (t/10)*10;
        float m = attn[k][uu][0];
        #pragma unroll
        for (int v2 = 1; v2 < 10; v2++) m = fmaxf(m, attn[k][uu][v2]);
        float e[10]; float ssum = 0.f;
        #pragma unroll
        for (int v2 = 0; v2 < 10; v2++) { e[v2] = __expf(attn[k][uu][v2] - m); ssum += e[v2]; }
        float inv = 1.f / ssum;
        #pragma unroll
        for (int v2 = 0; v2 < 10; v2++) Ar[k][uu][v2] = e[v2]*inv;
    } else if (t >= 64 && t < 104) {   // softmax over u -> Al
        int t2 = t - 64;
        int k = t2 / 10, vv = t2 - (t2/10)*10;
        float m = attn[k][0][vv];
        #pragma unroll
        for (int u2 = 1; u2 < 10; u2++) m = fmaxf(m, attn[k][u2][vv]);
        float e[10]; float ssum = 0.f;
        #pragma unroll
        for (int u2 = 0; u2 < 10; u2++) { e[u2] = __expf(attn[k][u2][vv] - m); ssum += e[u2]; }
        float inv = 1.f / ssum;
        #pragma unroll
        for (int u2 = 0; u2 < 10; u2++) Al[k][u2][vv] = e[u2]*inv;
    }
    __syncthreads();

    // ---- P4: F from register V (f32), half-exchange via shfl; pack fp16 k-pairs ----
    if (wv == 3) {          // Vr -> F_r2l*beta -> qf0 (input of side-0 dynamic conv)
        int k = ug >> 1, half = ug & 1, vb = half*5;
        float sc[8];
        #pragma unroll
        for (int r = 0; r < 8; r++) sc[r] = beta[ob + r];
        #pragma unroll
        for (int j2 = 0; j2 < 5; j2++) {
            int u1 = vb + j2;          // my output slice
            int u2 = 5 - vb + j2;      // partner's output slice
            float a1[5], a2[5];
            #pragma unroll
            for (int j = 0; j < 5; j++) { a1[j] = Ar[k][u1][vb+j]; a2[j] = Ar[k][u2][vb+j]; }
            float fv[8];
            #pragma unroll
            for (int r = 0; r < 8; r++) {
                float sA = 0.f, sB = 0.f;
                #pragma unroll
                for (int j = 0; j < 5; j++) {
                    sA = fmaf(a1[j], acc[r][j], sA);
                    sB = fmaf(a2[j], acc[r][j], sB);
                }
                float recv = __shfl_xor(sB, 8, 64);
                fv[r] = (sA + recv) * sc[r];
            }
            #pragma unroll
            for (int rr = 0; rr < 4; rr++)
                qf0[(og*4+rr)*XST + k*10 + u1] =
                    __builtin_amdgcn_cvt_pkrtz(fv[2*rr], fv[2*rr+1]);
        }
    } else if (wv == 2) {   // Vl -> F_l2r*gamma -> qf1 (input of side-1 dynamic conv)
        int k = ug >> 1, half = ug & 1, vb = half*5;
        float sc[8];
        #pragma unroll
        for (int r = 0; r < 8; r++) sc[r] = gamma[ob + r];
        #pragma unroll
        for (int j2 = 0; j2 < 5; j2++) {
            int u1 = vb + j2;
            int u2 = 5 - vb + j2;
            float a1[5], a2[5];
            #pragma unroll
            for (int j = 0; j < 5; j++) { a1[j] = Al[k][vb+j][u1]; a2[j] = Al[k][vb+j][u2]; }
            float fv[8];
            #pragma unroll
            for (int r = 0; r < 8; r++) {
                float sA = 0.f, sB = 0.f;
                #pragma unroll
                for (int j = 0; j < 5; j++) {
                    sA = fmaf(a1[j], acc[r][j], sA);
                    sB = fmaf(a2[j], acc[r][j], sB);
                }
                float recv = __shfl_xor(sB, 8, 64);
                fv[r] = (sA + recv) * sc[r];
            }
            #pragma unroll
            for (int rr = 0; rr < 4; rr++)
                qf1[(og*4+rr)*XST + k*10 + u1] =
                    __builtin_amdgcn_cvt_pkrtz(fv[2*rr], fv[2*rr+1]);
        }
    }
    __syncthreads();

    // ---- P5: dynamic conv via dot2 + residual(global, fp32 exact) + store ----
    // wave = (side, o-half): waves 0,1 -> side 0; 2,3 -> side 1
    {
        int side = wv >> 1;
        int oh   = wv & 1;
        int ob4  = oh*32 + og*4;
        const h2* Fb = side ? qf1 : qf0;
        const h2* wrow = g_waggTh + (size_t)(side*4 + b)*2048;
        const float* xsrc = side ? xr_g : xl_g;

        // prefetch residual (exact fp32 x), latency hides under the GEMM
        float res[4][5];
        #pragma unroll
        for (int r = 0; r < 4; r++) {
            const float* rp = xsrc + (size_t)(b*64 + ob4 + r)*HW_ + (size_t)h*WWD + w0 + ub;
            #pragma unroll
            for (int j = 0; j < 5; j++) res[r][j] = rp[j];
        }

        float acc5[4][5];
        #pragma unroll
        for (int r = 0; r < 4; r++)
            #pragma unroll
            for (int j = 0; j < 5; j++) acc5[r][j] = 0.f;
        __builtin_amdgcn_s_setprio(1);
        for (int m = 0; m < 32; m++) {
            U4 wu;
            wu.f = *(const float4*)(wrow + m*64 + ob4);
            h2 xv[5];
            const h2* frow = Fb + m*XST + ub;
            #pragma unroll
            for (int j = 0; j < 5; j++) xv[j] = frow[j];
            #pragma unroll
            for (int r = 0; r < 4; r++)
                #pragma unroll
                for (int j = 0; j < 5; j++)
                    acc5[r][j] = __builtin_amdgcn_fdot2(wu.h[r], xv[j], acc5[r][j], false);
        }
        __builtin_amdgcn_s_setprio(0);
        #pragma unroll
        for (int r = 0; r < 4; r++) {
            int o = ob4 + r;
            float bg = g_bagg[side*256 + b*64 + o];
            float* op = out + (size_t)side*TENSOR_ + (((size_t)(b*64+o)*HH + h)*WWD + w0 + ub);
            #pragma unroll
            for (int j = 0; j < 5; j++)
                op[j] = acc5[r][j] + bg + res[r][j];
        }
    }
}

extern "C" void kernel_launch(void* const* d_in, const int* in_sizes, int n_in,
                              void* d_out, int out_size, void* d_ws, size_t ws_size,
                              hipStream_t stream) {
    (void)in_sizes; (void)n_in; (void)out_size; (void)d_ws; (void)ws_size;
    const float* x_l = (const float*)d_in[0];
    const float* x_r = (const float*)d_in[1];

    gap_kernel<<<512, 256, 0, stream>>>(x_l, x_r);
    prep_kernel<<<17, 256, 0, stream>>>(
        (const float*)d_in[2],  (const float*)d_in[3],
        (const float*)d_in[4],  (const float*)d_in[5],
        (const float*)d_in[6],  (const float*)d_in[8],
        (const float*)d_in[10], (const float*)d_in[12],
        (const float*)d_in[16], (const float*)d_in[17],
        (const float*)d_in[18], (const float*)d_in[19], (const float*)d_in[21],
        (const float*)d_in[22], (const float*)d_in[23],
        (const float*)d_in[24], (const float*)d_in[25], (const float*)d_in[27],
        (const float*)d_in[20], (const float*)d_in[26]);
    main_kernel<<<BB*HH*8, 256, 0, stream>>>(x_l, x_r,
        (const float*)d_in[7],  (const float*)d_in[9],
        (const float*)d_in[11], (const float*)d_in[13],
        (const float*)d_in[14], (const float*)d_in[15],
        (float*)d_out);
}

// Round 4
// 388.590 us; speedup vs baseline: 1.2862x; 1.1233x over previous
//
#include <hip/hip_runtime.h>

typedef unsigned int u32;
typedef __fp16 h2  __attribute__((ext_vector_type(2)));
typedef __fp16 v8h __attribute__((ext_vector_type(8)));
typedef float  f32x4 __attribute__((ext_vector_type(4)));

#define BB 4
#define HH 180
#define WWD 320
#define HW_ 57600            // H*W
#define TENSOR_ 14745600     // B*C*H*W

union U4 { float4 f; v8h h8; h2 h[4]; };

// ---- module-scope scratch ----
__device__ __align__(16) float g_gap[512];      // [side][b][c]
__device__ __align__(16) float g_bagg[512];     // [side][b][o]
__device__ __align__(16) float g_swn[128];      // [side][o] sum of rounded folded w1
__device__ __align__(16) float g_sb[128];       // [side][o] = sum(w1*nb) + p1b
__device__ __align__(16) float g_vb[128];       // [side][o] = p2b
__device__ __align__(16) h2 g_w1fH[4096];       // [side][o][m] LN-folded p1 (i-pairs, row-major o x i)
__device__ __align__(16) h2 g_p2H[4096];        // [side][o][m] p2
__device__ __align__(16) h2 g_waggH[16384];     // [side][b][o][m] dyn conv W

// ---------------- kernel 1: global average pool -> g_gap
__global__ __launch_bounds__(256) void gap_kernel(const float* __restrict__ xl,
                                                  const float* __restrict__ xr) {
    int job = blockIdx.x;                 // side*256 + b*64 + c
    int side = job >> 8;
    int bc = job & 255;
    const float4* p = (const float4*)((side ? xr : xl) + (size_t)bc * HW_);
    float s = 0.f;
    for (int i = threadIdx.x; i < 14400; i += 256) {
        float4 v = p[i];
        s += v.x + v.y + v.z + v.w;
    }
    #pragma unroll
    for (int off = 32; off > 0; off >>= 1) s += __shfl_down(s, off, 64);
    __shared__ float red[4];
    int lane = threadIdx.x & 63, wv = threadIdx.x >> 6;
    if (lane == 0) red[wv] = s;
    __syncthreads();
    if (threadIdx.x == 0)
        g_gap[job] = (red[0] + red[1] + red[2] + red[3]) * (1.f / 57600.f);
}

// ---------------- kernel 2: expert mixture + fp16 row-major weight tables + bagg
__global__ __launch_bounds__(256) void prep_kernel(
    const float* __restrict__ nlw, const float* __restrict__ nlb,
    const float* __restrict__ nrw, const float* __restrict__ nrb,
    const float* __restrict__ lp1w, const float* __restrict__ rp1w,
    const float* __restrict__ lp2w, const float* __restrict__ rp2w,
    const float* __restrict__ lp1b, const float* __restrict__ rp1b,
    const float* __restrict__ lp2b, const float* __restrict__ rp2b,
    const float* __restrict__ lf1w, const float* __restrict__ lf1b,
    const float* __restrict__ lf2w, const float* __restrict__ lf2b,
    const float* __restrict__ lfbias,
    const float* __restrict__ rf1w, const float* __restrict__ rf1b,
    const float* __restrict__ rf2w, const float* __restrict__ rf2b,
    const float* __restrict__ rfbias,
    const float* __restrict__ lfW, const float* __restrict__ rfW)
{
    __shared__ float att[2][4][3];
    int t = threadIdx.x;
    if (t < 8) {
        int side = t >> 2, b = t & 3;
        const float* f1w = side ? rf1w : lf1w;
        const float* f1b = side ? rf1b : lf1b;
        const float* f2w = side ? rf2w : lf2w;
        const float* f2bv = side ? rf2b : lf2b;
        const float* g = g_gap + side*256 + b*64;
        float a1[3];
        #pragma unroll
        for (int k = 0; k < 3; k++) {
            float s = f1b[k];
            for (int c = 0; c < 64; c++) s += g[c] * f1w[k*64 + c];
            a1[k] = fmaxf(s, 0.f);
        }
        float a2[3];
        #pragma unroll
        for (int j = 0; j < 3; j++) {
            float s = f2bv[j];
            #pragma unroll
            for (int k = 0; k < 3; k++) s += a1[k] * f2w[j*3 + k];
            a2[j] = s;
        }
        float m = fmaxf(fmaxf(a2[0], a2[1]), a2[2]);
        float e0 = __expf(a2[0]-m), e1 = __expf(a2[1]-m), e2 = __expf(a2[2]-m);
        float inv = 1.f / (e0 + e1 + e2);
        att[side][b][0] = e0*inv; att[side][b][1] = e1*inv; att[side][b][2] = e2*inv;
    }
    __syncthreads();

    if (blockIdx.x < 16) {
        // wagg fp16 row-major [side][b][o][i-pairs m]
        int flat = blockIdx.x * 256 + t;     // 4096 jobs
        int row = flat >> 3, seg = flat & 7; // row = (side*4+b)*64 + o
        int side = row >> 8, bb = (row >> 6) & 3, o = row & 63;
        const float* Wp = side ? rfW : lfW;
        float a0 = att[side][bb][0], a1 = att[side][bb][1], a2 = att[side][bb][2];
        #pragma unroll
        for (int e = 0; e < 4; e++) {
            int m = seg*4 + e;
            int i0 = 2*m;
            float wi0 = a0*Wp[o*64+i0]   + a1*Wp[4096+o*64+i0]   + a2*Wp[8192+o*64+i0];
            float wi1 = a0*Wp[o*64+i0+1] + a1*Wp[4096+o*64+i0+1] + a2*Wp[8192+o*64+i0+1];
            g_waggH[row*32 + m] = __builtin_amdgcn_cvt_pkrtz(wi0, wi1);
        }
    } else {
        if (t < 128) {
            int side = t >> 6, o = t & 63;
            const float* w1 = side ? rp1w : lp1w;
            const float* w2 = side ? rp2w : lp2w;
            const float* nw = side ? nrw : nlw;
            const float* nb = side ? nrb : nlb;
            const float* b1 = side ? rp1b : lp1b;
            const float* b2 = side ? rp2b : lp2b;
            float s_wn = 0.f, s_b = 0.f;
            for (int m = 0; m < 32; m++) {
                float wf0 = w1[o*64 + 2*m],   wf1 = w1[o*64 + 2*m+1];
                h2 hw = __builtin_amdgcn_cvt_pkrtz(wf0 * nw[2*m], wf1 * nw[2*m+1]);
                g_w1fH[(side*64 + o)*32 + m] = hw;
                g_p2H [(side*64 + o)*32 + m] =
                    __builtin_amdgcn_cvt_pkrtz(w2[o*64+2*m], w2[o*64+2*m+1]);
                s_wn += (float)hw.x + (float)hw.y;   // consistent with rounded weights
                s_b  += wf0*nb[2*m] + wf1*nb[2*m+1];
            }
            g_swn[side*64 + o] = s_wn;
            g_sb[side*64 + o]  = s_b + b1[o];
            g_vb[side*64 + o]  = b2[o];
        }
        for (int idx = t; idx < 512; idx += 256) {
            int side = idx >> 8, r = idx & 255, b = r >> 6, o = r & 63;
            const float* bp = side ? rfbias : lfbias;
            g_bagg[idx] = att[side][b][0]*bp[o]
                        + att[side][b][1]*bp[64+o]
                        + att[side][b][2]*bp[128+o];
        }
    }
}

// ---------------- kernel 3: fused, MFMA-based.
// block = one (b,h) row x 40 px; 4 waves; all matmuls on v_mfma_f32_16x16x32_f16.
// Layout rule: every operand stored [non-K dim][K] row-major fp16; A and B frags
// read with the SAME k-addressing (k = kt*32 + (lane>>4)*8 + j) -> result invariant
// to the HW's internal k-permutation. D: col = lane&15, row = (lane>>4)*4 + reg.
__global__ __launch_bounds__(256, 4) void main_kernel(
    const float* __restrict__ xl_g, const float* __restrict__ xr_g,
    const float* __restrict__ beta, const float* __restrict__ gamma,
    float* __restrict__ out)
{
    __shared__ __align__(16) h2 xA[2][48][36];        // [side][px][i-pair]; later V^T overlay
    __shared__ __align__(16) __fp16 qA[2][48][72];    // [side][px][c] Q^T; later F^T
    __shared__ float attn[4][10][10];
    __shared__ __align__(16) __fp16 AH[2][4][16][32]; // [dir][ch][row][k16..31 zero-padded]
    __shared__ float muS[2][48], rsS[2][48];

    int t = threadIdx.x;
    int wv = t >> 6, lane = t & 63;
    int g16 = lane >> 4, i16 = lane & 15;
    int bid = blockIdx.x;
    int b  = bid / (HH*8);
    int r0 = bid % (HH*8);
    int h  = r0 / 8;
    int g  = r0 % 8;
    int w0 = g * 40;

    f32x4 z4; z4[0]=0.f; z4[1]=0.f; z4[2]=0.f; z4[3]=0.f;

    // ---- P0: stage x -> xA [side][px][i-pair] fp16; zero px pads 40..47 ----
    for (int idx = t; idx < 1216; idx += 256) {
        if (idx < 640) {
            int tensor = idx / 320;
            int r2 = idx - tensor*320;
            int m = r2 / 10, seg = r2 - m*10;
            const float* src = (tensor ? xr_g : xl_g)
                             + (((size_t)(b*64 + 2*m)*HH + h)*WWD + w0 + seg*4);
            float4 a = *(const float4*)(src);
            float4 c = *(const float4*)(src + HW_);    // odd channel, same pixels
            xA[tensor][seg*4+0][m] = __builtin_amdgcn_cvt_pkrtz(a.x, c.x);
            xA[tensor][seg*4+1][m] = __builtin_amdgcn_cvt_pkrtz(a.y, c.y);
            xA[tensor][seg*4+2][m] = __builtin_amdgcn_cvt_pkrtz(a.z, c.z);
            xA[tensor][seg*4+3][m] = __builtin_amdgcn_cvt_pkrtz(a.w, c.w);
        } else {
            int z = idx - 640;
            int side = z / 288, rr = z - side*288;
            int row = 40 + rr/36, col = rr - (rr/36)*36;
            h2 hz; hz.x = (__fp16)0.f; hz.y = (__fp16)0.f;
            xA[side][row][col] = hz;
        }
    }
    __syncthreads();

    // ---- P1: LN stats per px row (incl pads -> mu=0, rs finite) ----
    if (t < 96) {
        int side = t / 48, u = t - side*48;
        const h2* row = &xA[side][u][0];
        h2 one2; one2.x = (__fp16)1.f; one2.y = (__fp16)1.f;
        float s = 0.f, s2 = 0.f;
        #pragma unroll
        for (int q = 0; q < 8; q++) {
            U4 v; v.f = *(const float4*)(row + q*4);
            #pragma unroll
            for (int e = 0; e < 4; e++) {
                s  = __builtin_amdgcn_fdot2(v.h[e], one2,   s,  false);
                s2 = __builtin_amdgcn_fdot2(v.h[e], v.h[e], s2, false);
            }
        }
        float mu = s * (1.f/64.f);
        float var = fmaxf(s2 * (1.f/64.f) - mu*mu, 0.f);
        muS[side][u] = mu;
        rsS[side][u] = rsqrtf(var + 1e-6f);
    }
    __syncthreads();

    // ---- P2: projections via MFMA. wave: 0=Ql 1=Qr 2=Vl 3=Vr ----
    {
        int side = wv & 1;
        const h2* wTab = ((wv < 2) ? g_w1fH : g_p2H) + side*2048;   // [64][32] h2
        f32x4 acc[4][3];
        #pragma unroll
        for (int mt = 0; mt < 4; mt++)
            #pragma unroll
            for (int nt = 0; nt < 3; nt++) acc[mt][nt] = z4;

        __builtin_amdgcn_s_setprio(1);
        #pragma unroll
        for (int kt = 0; kt < 2; kt++) {
            U4 bf[3];
            #pragma unroll
            for (int nt = 0; nt < 3; nt++)
                bf[nt].f = *(const float4*)(&xA[side][nt*16 + i16][kt*16 + g16*4]);
            #pragma unroll
            for (int mt = 0; mt < 4; mt++) {
                U4 af; af.f = *(const float4*)(wTab + (mt*16 + i16)*32 + kt*16 + g16*4);
                #pragma unroll
                for (int nt = 0; nt < 3; nt++)
                    acc[mt][nt] = __builtin_amdgcn_mfma_f32_16x16x32_f16(
                        af.h8, bf[nt].h8, acc[mt][nt], 0, 0, 0);
            }
        }
        __builtin_amdgcn_s_setprio(0);
        __syncthreads();   // all xA raw-x reads done before V^T overlay

        if (wv < 2) {      // Q epilogue: LN fold -> qA[side][u][c]
            #pragma unroll
            for (int nt = 0; nt < 3; nt++) {
                int u = nt*16 + i16;
                float mu = muS[side][u], rs = rsS[side][u];
                #pragma unroll
                for (int mt = 0; mt < 4; mt++) {
                    float4 swl = *(const float4*)&g_swn[side*64 + mt*16 + g16*4];
                    float4 sbl = *(const float4*)&g_sb [side*64 + mt*16 + g16*4];
                    f32x4 a = acc[mt][nt];
                    float e0 = rs*(a[0] - mu*swl.x) + sbl.x;
                    float e1 = rs*(a[1] - mu*swl.y) + sbl.y;
                    float e2 = rs*(a[2] - mu*swl.z) + sbl.z;
                    float e3 = rs*(a[3] - mu*swl.w) + sbl.w;
                    h2* dst = (h2*)&qA[side][u][mt*16 + g16*4];
                    dst[0] = __builtin_amdgcn_cvt_pkrtz(e0, e1);
                    dst[1] = __builtin_amdgcn_cvt_pkrtz(e2, e3);
                }
            }
        } else {           // V epilogue: +bias -> V^T[px][o] overlaid on xA
            __fp16* vTp = (__fp16*)xA;
            #pragma unroll
            for (int nt = 0; nt < 3; nt++) {
                int px = nt*16 + i16;
                #pragma unroll
                for (int mt = 0; mt < 4; mt++) {
                    float4 vb = *(const float4*)&g_vb[side*64 + mt*16 + g16*4];
                    f32x4 a = acc[mt][nt];
                    h2* dst = (h2*)&vTp[((size_t)side*48 + px)*72 + mt*16 + g16*4];
                    dst[0] = __builtin_amdgcn_cvt_pkrtz(a[0]+vb.x, a[1]+vb.y);
                    dst[1] = __builtin_amdgcn_cvt_pkrtz(a[2]+vb.z, a[3]+vb.w);
                }
            }
        }
    }
    __syncthreads();

    // ---- P3: scores S = Ql^T Qr per 10-chunk; wave = chunk ----
    {
        const __fp16* ra = &qA[0][wv*10 + i16][0];
        const __fp16* rb = &qA[1][wv*10 + i16][0];
        f32x4 s = z4;
        #pragma unroll
        for (int kt = 0; kt < 2; kt++) {
            U4 af, bf;
            af.f = *(const float4*)(ra + kt*32 + g16*8);
            bf.f = *(const float4*)(rb + kt*32 + g16*8);
            s = __builtin_amdgcn_mfma_f32_16x16x32_f16(af.h8, bf.h8, s, 0, 0, 0);
        }
        #pragma unroll
        for (int reg = 0; reg < 4; reg++) {
            int r = g16*4 + reg;
            if (r < 10 && i16 < 10) attn[wv][r][i16] = s[reg] * 0.125f;
        }
    }
    __syncthreads();

    // ---- softmax -> AH fp16 rows, K-pad zeroed ----
    if (t < 40) {                      // over v -> ArH = AH[0][ch][u][v0..31]
        int k = t / 10, uu = t - (t/10)*10;
        float m = attn[k][uu][0];
        #pragma unroll
        for (int v2 = 1; v2 < 10; v2++) m = fmaxf(m, attn[k][uu][v2]);
        float e[10]; float ssum = 0.f;
        #pragma unroll
        for (int v2 = 0; v2 < 10; v2++) { e[v2] = __expf(attn[k][uu][v2] - m); ssum += e[v2]; }
        float inv = 1.f / ssum;
        h2 hz; hz.x = (__fp16)0.f; hz.y = (__fp16)0.f;
        U4 r0_, r1_;
        r0_.h[0] = __builtin_amdgcn_cvt_pkrtz(e[0]*inv, e[1]*inv);
        r0_.h[1] = __builtin_amdgcn_cvt_pkrtz(e[2]*inv, e[3]*inv);
        r0_.h[2] = __builtin_amdgcn_cvt_pkrtz(e[4]*inv, e[5]*inv);
        r0_.h[3] = __builtin_amdgcn_cvt_pkrtz(e[6]*inv, e[7]*inv);
        r1_.h[0] = __builtin_amdgcn_cvt_pkrtz(e[8]*inv, e[9]*inv);
        r1_.h[1] = hz; r1_.h[2] = hz; r1_.h[3] = hz;
        float4 zf = make_float4(0.f,0.f,0.f,0.f);
        float4* dst = (float4*)&AH[0][k][uu][0];
        dst[0] = r0_.f; dst[1] = r1_.f; dst[2] = zf; dst[3] = zf;
    } else if (t >= 64 && t < 104) {   // over u -> AlH = AH[1][ch][v][u0..31]
        int t2 = t - 64;
        int k = t2 / 10, vv = t2 - (t2/10)*10;
        float m = attn[k][0][vv];
        #pragma unroll
        for (int u2 = 1; u2 < 10; u2++) m = fmaxf(m, attn[k][u2][vv]);
        float e[10]; float ssum = 0.f;
        #pragma unroll
        for (int u2 = 0; u2 < 10; u2++) { e[u2] = __expf(attn[k][u2][vv] - m); ssum += e[u2]; }
        float inv = 1.f / ssum;
        h2 hz; hz.x = (__fp16)0.f; hz.y = (__fp16)0.f;
        U4 r0_, r1_;
        r0_.h[0] = __builtin_amdgcn_cvt_pkrtz(e[0]*inv, e[1]*inv);
        r0_.h[1] = __builtin_amdgcn_cvt_pkrtz(e[2]*inv, e[3]*inv);
        r0_.h[2] = __builtin_amdgcn_cvt_pkrtz(e[4]*inv, e[5]*inv);
        r0_.h[3] = __builtin_amdgcn_cvt_pkrtz(e[6]*inv, e[7]*inv);
        r1_.h[0] = __builtin_amdgcn_cvt_pkrtz(e[8]*inv, e[9]*inv);
        r1_.h[1] = hz; r1_.h[2] = hz; r1_.h[3] = hz;
        float4 zf = make_float4(0.f,0.f,0.f,0.f);
        float4* dst = (float4*)&AH[1][k][vv][0];
        dst[0] = r0_.f; dst[1] = r1_.f; dst[2] = zf; dst[3] = zf;
    }
    __syncthreads();

    // ---- residual prefetch (for P5; hides HBM latency under P4) ----
    int side5 = wv >> 1, mth = wv & 1;
    const float* xsrc = side5 ? xr_g : xl_g;
    float res[2][3][4];
    #pragma unroll
    for (int m2 = 0; m2 < 2; m2++)
        #pragma unroll
        for (int nt = 0; nt < 3; nt++) {
            int px = nt*16 + i16;
            #pragma unroll
            for (int reg = 0; reg < 4; reg++) {
                int o = mth*32 + m2*16 + g16*4 + reg;
                res[m2][nt][reg] = (px < 40)
                    ? xsrc[(size_t)(b*64+o)*HW_ + (size_t)h*WWD + w0 + px] : 0.f;
            }
        }

    // ---- P4: F = A x V via MFMA; dir0: F_r2l (ArH x Vr) -> qA[0]; dir1: F_l2r -> qA[1] ----
    {
        int dir = wv >> 1, mth4 = wv & 1, vside = dir ^ 1;
        const float* scp = dir ? gamma : beta;
        const __fp16* vTp = (const __fp16*)xA;
        #pragma unroll
        for (int ch = 0; ch < 4; ch++) {
            #pragma unroll
            for (int m2 = 0; m2 < 2; m2++) {
                int mt = mth4*2 + m2;
                U4 af;
                #pragma unroll
                for (int j = 0; j < 8; j++) {
                    int vv = ch*10 + g16*8 + j;
                    vv = vv > 47 ? 47 : vv;   // clamp: B is zero there anyway
                    af.h[j>>1][j&1] = vTp[((size_t)vside*48 + vv)*72 + mt*16 + i16];
                }
                U4 bf; bf.f = *(const float4*)&AH[dir][ch][i16][g16*8];
                f32x4 d = __builtin_amdgcn_mfma_f32_16x16x32_f16(af.h8, bf.h8, z4, 0, 0, 0);
                if (i16 < 10) {
                    int px = ch*10 + i16;
                    float4 sc = *(const float4*)&scp[mt*16 + g16*4];
                    h2* dst = (h2*)&qA[dir][px][mt*16 + g16*4];
                    dst[0] = __builtin_amdgcn_cvt_pkrtz(d[0]*sc.x, d[1]*sc.y);
                    dst[1] = __builtin_amdgcn_cvt_pkrtz(d[2]*sc.z, d[3]*sc.w);
                }
            }
        }
    }
    __syncthreads();

    // ---- P5: dynamic conv via MFMA + bagg + residual; wave = (side, o-half) ----
    {
        const h2* wag = g_waggH + (size_t)((side5*4 + b)*64 + mth*32)*32;
        f32x4 acc[2][3];
        #pragma unroll
        for (int m2 = 0; m2 < 2; m2++)
            #pragma unroll
            for (int nt = 0; nt < 3; nt++) acc[m2][nt] = z4;

        __builtin_amdgcn_s_setprio(1);
        #pragma unroll
        for (int kt = 0; kt < 2; kt++) {
            U4 bf[3];
            #pragma unroll
            for (int nt = 0; nt < 3; nt++)
                bf[nt].f = *(const float4*)(&qA[side5][nt*16 + i16][kt*32 + g16*8]);
            #pragma unroll
            for (int m2 = 0; m2 < 2; m2++) {
                U4 af; af.f = *(const float4*)(wag + (m2*16 + i16)*32 + kt*16 + g16*4);
                #pragma unroll
                for (int nt = 0; nt < 3; nt++)
                    acc[m2][nt] = __builtin_amdgcn_mfma_f32_16x16x32_f16(
                        af.h8, bf[nt].h8, acc[m2][nt], 0, 0, 0);
            }
        }
        __builtin_amdgcn_s_setprio(0);

        #pragma unroll
        for (int m2 = 0; m2 < 2; m2++) {
            float4 bg = *(const float4*)&g_bagg[side5*256 + b*64 + mth*32 + m2*16 + g16*4];
            float bga[4] = {bg.x, bg.y, bg.z, bg.w};
            #pragma unroll
            for (int nt = 0; nt < 3; nt++) {
                int px = nt*16 + i16;
                if (px < 40) {
                    #pragma unroll
                    for (int reg = 0; reg < 4; reg++) {
                        int o = mth*32 + m2*16 + g16*4 + reg;
                        out[(size_t)side5*TENSOR_ + (size_t)(b*64+o)*HW_ + (size_t)h*WWD + w0 + px]
                            = acc[m2][nt][reg] + bga[reg] + res[m2][nt][reg];
                    }
                }
            }
        }
    }
}

extern "C" void kernel_launch(void* const* d_in, const int* in_sizes, int n_in,
                              void* d_out, int out_size, void* d_ws, size_t ws_size,
                              hipStream_t stream) {
    (void)in_sizes; (void)n_in; (void)out_size; (void)d_ws; (void)ws_size;
    const float* x_l = (const float*)d_in[0];
    const float* x_r = (const float*)d_in[1];

    gap_kernel<<<512, 256, 0, stream>>>(x_l, x_r);
    prep_kernel<<<17, 256, 0, stream>>>(
        (const float*)d_in[2],  (const float*)d_in[3],
        (const float*)d_in[4],  (const float*)d_in[5],
        (const float*)d_in[6],  (const float*)d_in[8],
        (const float*)d_in[10], (const float*)d_in[12],
        (const float*)d_in[7],  (const float*)d_in[9],
        (const float*)d_in[11], (const float*)d_in[13],
        (const float*)d_in[16], (const float*)d_in[17],
        (const float*)d_in[18], (const float*)d_in[19], (const float*)d_in[21],
        (const float*)d_in[22], (const float*)d_in[23],
        (const float*)d_in[24], (const float*)d_in[25], (const float*)d_in[27],
        (const float*)d_in[20], (const float*)d_in[26]);
    main_kernel<<<BB*HH*8, 256, 0, stream>>>(x_l, x_r,
        (const float*)d_in[14], (const float*)d_in[15],
        (float*)d_out);
}